// Round 1
// baseline (202.790 us; speedup 1.0000x reference)
//
#include <hip/hip_runtime.h>
#include <hip/hip_bf16.h>

#define B_ 8
#define S_ 2048
#define D_ 256
#define U_ 128
#define BS_ (B_*S_)

using bf16 = __hip_bfloat16;
typedef __attribute__((ext_vector_type(8))) __bf16 bf8v;      // MFMA A/B frag (4 VGPR)
typedef __attribute__((ext_vector_type(4))) float f4v;        // MFMA C/D frag
typedef __attribute__((ext_vector_type(4))) float float4v;
typedef __attribute__((ext_vector_type(4))) unsigned short us4;

#define MFMA16(a,b,c) __builtin_amdgcn_mfma_f32_16x16x32_bf16((a),(b),(c),0,0,0)

__device__ __forceinline__ unsigned short f2bits(float f){
  return __builtin_bit_cast(unsigned short, __float2bfloat16(f));
}

// ---------------- prep: X fp32 -> bf16 ----------------
__global__ __launch_bounds__(256) void convert_x_kernel(const float* __restrict__ X,
                                                        unsigned short* __restrict__ Xb){
  int i = blockIdx.x*256 + threadIdx.x;             // BS_*D_/4 threads
  float4v v = reinterpret_cast<const float4v*>(X)[i];
  us4 r;
  r[0]=f2bits(v[0]); r[1]=f2bits(v[1]); r[2]=f2bits(v[2]); r[3]=f2bits(v[3]);
  reinterpret_cast<us4*>(Xb)[i] = r;
}

// ---------------- prep: weight transpose+convert ----------------
// Wq/Wk/Wv [D,U] fp32 -> Wt [U,D] bf16 ; Wo [U,D] fp32 -> Wot [D,U] bf16
__global__ __launch_bounds__(256) void prep_w_kernel(const float* __restrict__ Wq,
                                                     const float* __restrict__ Wk,
                                                     const float* __restrict__ Wv,
                                                     const float* __restrict__ Wo,
                                                     bf16* __restrict__ Wqt,
                                                     bf16* __restrict__ Wkt,
                                                     bf16* __restrict__ Wvt,
                                                     bf16* __restrict__ Wot){
  int t = blockIdx.x*256 + threadIdx.x;             // 4*32768 threads
  int s = t >> 15;
  int idx = t & 32767;
  if (s < 3){
    const float* src = (s==0)?Wq:((s==1)?Wk:Wv);
    bf16* dst = (s==0)?Wqt:((s==1)?Wkt:Wvt);
    int u = idx >> 8;          // /D_ = 256
    int d = idx & 255;
    dst[(size_t)u*D_ + d] = __float2bfloat16(src[(size_t)d*U_ + u]);
  } else {
    int dd = idx >> 7;         // /U_ = 128
    int u  = idx & 127;
    Wot[(size_t)dd*U_ + u] = __float2bfloat16(Wo[(size_t)u*D_ + dd]);
  }
}

// ---------------- QKV projection GEMM ----------------
// Xb [BS,D] bf16 @ Wt^T ([U,D] bf16) -> Q/K row-major [BS,U] bf16, V transposed [B][U][S] bf16
__global__ __launch_bounds__(256) void qkv_kernel(const bf16* __restrict__ Xb,
                                                  const bf16* __restrict__ Wqt,
                                                  const bf16* __restrict__ Wkt,
                                                  const bf16* __restrict__ Wvt,
                                                  bf16* __restrict__ Q,
                                                  bf16* __restrict__ K,
                                                  bf16* __restrict__ Vt){
  const int which = blockIdx.y;
  const bf16* Wt = (which==0) ? Wqt : ((which==1) ? Wkt : Wvt);
  const int w    = threadIdx.x >> 6;
  const int lane = threadIdx.x & 63;
  const int lq   = lane & 15;
  const int g    = lane >> 4;
  const int m0   = blockIdx.x*64 + w*16;

  f4v acc[8];
  #pragma unroll
  for (int i=0;i<8;i++) acc[i] = (f4v){0.f,0.f,0.f,0.f};

  const bf16* xp = Xb + (size_t)(m0+lq)*D_ + g*8;
  #pragma unroll
  for (int k0=0;k0<D_;k0+=32){
    bf8v a = *reinterpret_cast<const bf8v*>(xp + k0);
    #pragma unroll
    for (int nc=0;nc<8;nc++){
      bf8v b = *reinterpret_cast<const bf8v*>(Wt + (size_t)(nc*16+lq)*D_ + k0 + g*8);
      acc[nc] = MFMA16(a, b, acc[nc]);
    }
  }

  if (which==0){
    const float qscale = 0.08838834764831845f;      // 1/sqrt(U)
    #pragma unroll
    for (int nc=0;nc<8;nc++){
      #pragma unroll
      for (int r=0;r<4;r++){
        Q[(size_t)(m0+g*4+r)*U_ + nc*16+lq] = __float2bfloat16(acc[nc][r]*qscale);
      }
    }
  } else if (which==1){
    #pragma unroll
    for (int nc=0;nc<8;nc++){
      #pragma unroll
      for (int r=0;r<4;r++){
        K[(size_t)(m0+g*4+r)*U_ + nc*16+lq] = __float2bfloat16(acc[nc][r]);
      }
    }
  } else {
    #pragma unroll
    for (int nc=0;nc<8;nc++){
      #pragma unroll
      for (int r=0;r<4;r++){
        int m = m0 + g*4 + r;
        int b = m >> 11;               // /S_
        int s = m & (S_-1);
        Vt[((size_t)b*U_ + nc*16+lq)*S_ + s] = __float2bfloat16(acc[nc][r]);
      }
    }
  }
}

// ---------------- flash attention ----------------
// Per WG: batch blockIdx.y, 64 q-rows; wave owns 16 q-rows. KV block = 32.
// S^T = mfma(K, Q): C frag holds col q=lane&15, row k=(lane>>4)*4+r.
__global__ __launch_bounds__(256) void flash_kernel(const bf16* __restrict__ Q,
                                                    const bf16* __restrict__ K,
                                                    const bf16* __restrict__ Vt,
                                                    bf16* __restrict__ O){
  __shared__ bf16 Plds[4][16][40];   // per-wave P tile [16q][32k], stride 40 (80B, 16B-aligned)

  const int b    = blockIdx.y;
  const int w    = threadIdx.x >> 6;
  const int lane = threadIdx.x & 63;
  const int lq   = lane & 15;
  const int g    = lane >> 4;
  const int q0   = blockIdx.x*64 + w*16;

  const bf16* Qp    = Q  + (size_t)(b*S_ + q0 + lq)*U_ + g*8;
  const bf16* Kbase = K  + (size_t)b*S_*U_ + (size_t)lq*U_ + g*8;
  const bf16* Vbase = Vt + (size_t)b*U_*S_ + (size_t)lq*S_ + g*8;

  bf8v qf[4];
  #pragma unroll
  for (int uc=0;uc<4;uc++) qf[uc] = *reinterpret_cast<const bf8v*>(Qp + uc*32);

  f4v o[8];
  #pragma unroll
  for (int i=0;i<8;i++) o[i] = (f4v){0.f,0.f,0.f,0.f};
  float mrow = -1e30f, lrow = 0.f;

  unsigned short* prow = reinterpret_cast<unsigned short*>(&Plds[w][lq][0]);

  for (int k0=0; k0<S_; k0+=32){
    f4v st0 = (f4v){0.f,0.f,0.f,0.f};
    f4v st1 = (f4v){0.f,0.f,0.f,0.f};
    const bf16* kp = Kbase + (size_t)k0*U_;
    #pragma unroll
    for (int uc=0;uc<4;uc++){
      bf8v kf0 = *reinterpret_cast<const bf8v*>(kp + uc*32);
      bf8v kf1 = *reinterpret_cast<const bf8v*>(kp + 16*U_ + uc*32);
      st0 = MFMA16(kf0, qf[uc], st0);
      st1 = MFMA16(kf1, qf[uc], st1);
    }
    // tile max over k (this block) for fixed q=lq
    float tm = fmaxf(fmaxf(fmaxf(st0[0],st0[1]),fmaxf(st0[2],st0[3])),
                     fmaxf(fmaxf(st1[0],st1[1]),fmaxf(st1[2],st1[3])));
    tm = fmaxf(tm, __shfl_xor(tm, 16));
    tm = fmaxf(tm, __shfl_xor(tm, 32));
    float mn    = fmaxf(mrow, tm);
    float alpha = __expf(mrow - mn);
    float p0[4], p1[4];
    float ts = 0.f;
    #pragma unroll
    for (int r=0;r<4;r++){
      p0[r] = __expf(st0[r]-mn);
      p1[r] = __expf(st1[r]-mn);
      ts += p0[r] + p1[r];
    }
    ts += __shfl_xor(ts, 16);
    ts += __shfl_xor(ts, 32);
    lrow = lrow*alpha + ts;
    mrow = mn;

    // P -> LDS (bf16), layout [q][k]: st0 -> k=4g+r, st1 -> k=16+4g+r
    unsigned int w01 = (unsigned)f2bits(p0[0]) | ((unsigned)f2bits(p0[1])<<16);
    unsigned int w23 = (unsigned)f2bits(p0[2]) | ((unsigned)f2bits(p0[3])<<16);
    unsigned int x01 = (unsigned)f2bits(p1[0]) | ((unsigned)f2bits(p1[1])<<16);
    unsigned int x23 = (unsigned)f2bits(p1[2]) | ((unsigned)f2bits(p1[3])<<16);
    *reinterpret_cast<unsigned int*>(prow + 4*g)      = w01;
    *reinterpret_cast<unsigned int*>(prow + 4*g + 2)  = w23;
    *reinterpret_cast<unsigned int*>(prow + 16 + 4*g)     = x01;
    *reinterpret_cast<unsigned int*>(prow + 16 + 4*g + 2) = x23;

    // rescale O rows (rows of o-frag are q = g*4+r)
    float a0 = __shfl(alpha, g*4+0);
    float a1 = __shfl(alpha, g*4+1);
    float a2 = __shfl(alpha, g*4+2);
    float a3 = __shfl(alpha, g*4+3);
    #pragma unroll
    for (int uc=0;uc<8;uc++){
      o[uc][0]*=a0; o[uc][1]*=a1; o[uc][2]*=a2; o[uc][3]*=a3;
    }

    // P A-frag: lane holds P[q=lq][k=g*8+j]
    bf8v pa = *reinterpret_cast<const bf8v*>(&Plds[w][lq][g*8]);
    const bf16* vp = Vbase + k0;
    #pragma unroll
    for (int uc=0;uc<8;uc++){
      bf8v vf = *reinterpret_cast<const bf8v*>(vp + (size_t)uc*16*S_);
      o[uc] = MFMA16(pa, vf, o[uc]);
    }
  }

  float li = 1.0f / lrow;
  float l0 = __shfl(li, g*4+0);
  float l1 = __shfl(li, g*4+1);
  float l2 = __shfl(li, g*4+2);
  float l3 = __shfl(li, g*4+3);
  bf16* Op = O + (size_t)(b*S_ + q0)*U_;
  #pragma unroll
  for (int uc=0;uc<8;uc++){
    Op[(size_t)(g*4+0)*U_ + uc*16+lq] = __float2bfloat16(o[uc][0]*l0);
    Op[(size_t)(g*4+1)*U_ + uc*16+lq] = __float2bfloat16(o[uc][1]*l1);
    Op[(size_t)(g*4+2)*U_ + uc*16+lq] = __float2bfloat16(o[uc][2]*l2);
    Op[(size_t)(g*4+3)*U_ + uc*16+lq] = __float2bfloat16(o[uc][3]*l3);
  }
}

// ---------------- output projection + residual ----------------
// Y[BS,D] = O[BS,U] @ Wo[U,D] + b_o + X
__global__ __launch_bounds__(256) void oproj_kernel(const bf16* __restrict__ O,
                                                    const bf16* __restrict__ Wot,
                                                    const float* __restrict__ X,
                                                    const float* __restrict__ bo,
                                                    float* __restrict__ Y){
  const int w    = threadIdx.x >> 6;
  const int lane = threadIdx.x & 63;
  const int lq   = lane & 15;
  const int g    = lane >> 4;
  const int m0   = blockIdx.x*64 + w*16;

  f4v acc[16];
  #pragma unroll
  for (int i=0;i<16;i++) acc[i] = (f4v){0.f,0.f,0.f,0.f};

  const bf16* op = O + (size_t)(m0+lq)*U_ + g*8;
  #pragma unroll
  for (int k0=0;k0<U_;k0+=32){
    bf8v a = *reinterpret_cast<const bf8v*>(op + k0);
    #pragma unroll
    for (int nc=0;nc<16;nc++){
      bf8v bb = *reinterpret_cast<const bf8v*>(Wot + (size_t)(nc*16+lq)*U_ + k0 + g*8);
      acc[nc] = MFMA16(a, bb, acc[nc]);
    }
  }

  #pragma unroll
  for (int nc=0;nc<16;nc++){
    int col = nc*16 + lq;
    float bias = bo[col];
    #pragma unroll
    for (int r=0;r<4;r++){
      int row = m0 + g*4 + r;
      Y[(size_t)row*D_ + col] = acc[nc][r] + bias + X[(size_t)row*D_ + col];
    }
  }
}

extern "C" void kernel_launch(void* const* d_in, const int* in_sizes, int n_in,
                              void* d_out, int out_size, void* d_ws, size_t ws_size,
                              hipStream_t stream) {
  (void)in_sizes; (void)n_in; (void)out_size; (void)ws_size;
  const float* X  = (const float*)d_in[0];
  const float* Wq = (const float*)d_in[1];
  const float* Wk = (const float*)d_in[2];
  const float* Wv = (const float*)d_in[3];
  const float* Wo = (const float*)d_in[4];
  const float* bo = (const float*)d_in[5];
  float* Y = (float*)d_out;

  char* ws = (char*)d_ws;
  bf16* Xb  = (bf16*)(ws + 0);          // BS*D*2    = 8388608
  bf16* Qb  = (bf16*)(ws + 8388608);    // BS*U*2    = 4194304
  bf16* Kb  = (bf16*)(ws + 12582912);   // BS*U*2
  bf16* Vt  = (bf16*)(ws + 16777216);   // BS*U*2 (transposed per batch)
  bf16* Ob  = (bf16*)(ws + 20971520);   // BS*U*2
  bf16* Wqt = (bf16*)(ws + 25165824);   // U*D*2 = 65536
  bf16* Wkt = (bf16*)(ws + 25231360);
  bf16* Wvt = (bf16*)(ws + 25296896);
  bf16* Wot = (bf16*)(ws + 25362432);

  convert_x_kernel<<<dim3(BS_*D_/4/256), dim3(256), 0, stream>>>(X, (unsigned short*)Xb);
  prep_w_kernel<<<dim3(512), dim3(256), 0, stream>>>(Wq, Wk, Wv, Wo, Wqt, Wkt, Wvt, Wot);
  qkv_kernel<<<dim3(BS_/64, 3), dim3(256), 0, stream>>>(Xb, Wqt, Wkt, Wvt, Qb, Kb, Vt);
  flash_kernel<<<dim3(S_/64, B_), dim3(256), 0, stream>>>(Qb, Kb, Vt, Ob);
  oproj_kernel<<<dim3(BS_/64), dim3(256), 0, stream>>>(Ob, Wot, X, bo, Y);
}

// Round 2
// 171.245 us; speedup vs baseline: 1.1842x; 1.1842x over previous
//
#include <hip/hip_runtime.h>
#include <hip/hip_bf16.h>

#define B_ 8
#define S_ 2048
#define D_ 256
#define U_ 128
#define BS_ (B_*S_)

using bf16 = __hip_bfloat16;
typedef __attribute__((ext_vector_type(8))) __bf16 bf8v;      // MFMA A/B frag (4 VGPR)
typedef __attribute__((ext_vector_type(4))) float f4v;        // MFMA C/D frag
typedef __attribute__((ext_vector_type(4))) float float4v;
typedef __attribute__((ext_vector_type(4))) unsigned short us4;

#define MFMA16(a,b,c) __builtin_amdgcn_mfma_f32_16x16x32_bf16((a),(b),(c),0,0,0)

__device__ __forceinline__ unsigned short f2bits(float f){
  return __builtin_bit_cast(unsigned short, __float2bfloat16(f));
}

// ---------------- prep: X fp32 -> bf16 ----------------
__global__ __launch_bounds__(256) void convert_x_kernel(const float* __restrict__ X,
                                                        unsigned short* __restrict__ Xb){
  int i = blockIdx.x*256 + threadIdx.x;             // BS_*D_/4 threads
  float4v v = reinterpret_cast<const float4v*>(X)[i];
  us4 r;
  r[0]=f2bits(v[0]); r[1]=f2bits(v[1]); r[2]=f2bits(v[2]); r[3]=f2bits(v[3]);
  reinterpret_cast<us4*>(Xb)[i] = r;
}

// ---------------- prep: weight transpose+convert ----------------
__global__ __launch_bounds__(256) void prep_w_kernel(const float* __restrict__ Wq,
                                                     const float* __restrict__ Wk,
                                                     const float* __restrict__ Wv,
                                                     const float* __restrict__ Wo,
                                                     bf16* __restrict__ Wqt,
                                                     bf16* __restrict__ Wkt,
                                                     bf16* __restrict__ Wvt,
                                                     bf16* __restrict__ Wot){
  int t = blockIdx.x*256 + threadIdx.x;             // 4*32768 threads
  int s = t >> 15;
  int idx = t & 32767;
  if (s < 3){
    const float* src = (s==0)?Wq:((s==1)?Wk:Wv);
    bf16* dst = (s==0)?Wqt:((s==1)?Wkt:Wvt);
    int u = idx >> 8;          // /D_ = 256
    int d = idx & 255;
    dst[(size_t)u*D_ + d] = __float2bfloat16(src[(size_t)d*U_ + u]);
  } else {
    int dd = idx >> 7;         // /U_ = 128
    int u  = idx & 127;
    Wot[(size_t)dd*U_ + u] = __float2bfloat16(Wo[(size_t)u*D_ + dd]);
  }
}

// ---------------- QKV projection GEMM ----------------
__global__ __launch_bounds__(256) void qkv_kernel(const bf16* __restrict__ Xb,
                                                  const bf16* __restrict__ Wqt,
                                                  const bf16* __restrict__ Wkt,
                                                  const bf16* __restrict__ Wvt,
                                                  bf16* __restrict__ Q,
                                                  bf16* __restrict__ K,
                                                  bf16* __restrict__ Vt){
  const int which = blockIdx.y;
  const bf16* Wt = (which==0) ? Wqt : ((which==1) ? Wkt : Wvt);
  const int w    = threadIdx.x >> 6;
  const int lane = threadIdx.x & 63;
  const int lq   = lane & 15;
  const int g    = lane >> 4;
  const int m0   = blockIdx.x*64 + w*16;

  f4v acc[8];
  #pragma unroll
  for (int i=0;i<8;i++) acc[i] = (f4v){0.f,0.f,0.f,0.f};

  const bf16* xp = Xb + (size_t)(m0+lq)*D_ + g*8;
  #pragma unroll
  for (int k0=0;k0<D_;k0+=32){
    bf8v a = *reinterpret_cast<const bf8v*>(xp + k0);
    #pragma unroll
    for (int nc=0;nc<8;nc++){
      bf8v b = *reinterpret_cast<const bf8v*>(Wt + (size_t)(nc*16+lq)*D_ + k0 + g*8);
      acc[nc] = MFMA16(a, b, acc[nc]);
    }
  }

  if (which==0){
    const float qscale = 0.08838834764831845f;      // 1/sqrt(U)
    #pragma unroll
    for (int nc=0;nc<8;nc++){
      #pragma unroll
      for (int r=0;r<4;r++){
        Q[(size_t)(m0+g*4+r)*U_ + nc*16+lq] = __float2bfloat16(acc[nc][r]*qscale);
      }
    }
  } else if (which==1){
    #pragma unroll
    for (int nc=0;nc<8;nc++){
      #pragma unroll
      for (int r=0;r<4;r++){
        K[(size_t)(m0+g*4+r)*U_ + nc*16+lq] = __float2bfloat16(acc[nc][r]);
      }
    }
  } else {
    #pragma unroll
    for (int nc=0;nc<8;nc++){
      #pragma unroll
      for (int r=0;r<4;r++){
        int m = m0 + g*4 + r;
        int b = m >> 11;               // /S_
        int s = m & (S_-1);
        Vt[((size_t)b*U_ + nc*16+lq)*S_ + s] = __float2bfloat16(acc[nc][r]);
      }
    }
  }
}

// ---------------- flash attention, in-block split-KV ----------------
// 1 WG = 16 q-rows, 4 waves; wave w owns KV rows [w*512, w*512+512).
// Partials combined across waves via LDS at the end.
__global__ __launch_bounds__(256) void flash_kernel(const bf16* __restrict__ Q,
                                                    const bf16* __restrict__ K,
                                                    const bf16* __restrict__ Vt,
                                                    bf16* __restrict__ O){
  __shared__ bf16  Plds[4][16][40];    // per-wave P tile [16q][32k], stride 40
  __shared__ float oacc[4][16][132];   // per-wave scaled partial O (stride 132 vs bank conflicts)
  __shared__ float mlds[4][16];
  __shared__ float llds[4][16];

  const int b    = blockIdx.y;
  const int w    = threadIdx.x >> 6;
  const int lane = threadIdx.x & 63;
  const int lq   = lane & 15;
  const int g    = lane >> 4;
  const int q0   = blockIdx.x*16;

  const bf16* Qp    = Q  + (size_t)(b*S_ + q0 + lq)*U_ + g*8;
  const bf16* Kbase = K  + (size_t)b*S_*U_ + (size_t)lq*U_ + g*8;
  const bf16* Vbase = Vt + (size_t)b*U_*S_ + (size_t)lq*S_ + g*8;

  bf8v qf[4];
  #pragma unroll
  for (int uc=0;uc<4;uc++) qf[uc] = *reinterpret_cast<const bf8v*>(Qp + uc*32);

  f4v o[8];
  #pragma unroll
  for (int i=0;i<8;i++) o[i] = (f4v){0.f,0.f,0.f,0.f};
  float mrow = -1e30f, lrow = 0.f;

  unsigned short* prow = reinterpret_cast<unsigned short*>(&Plds[w][lq][0]);

  const int kbeg = w*(S_/4);
  const int kend = kbeg + (S_/4);
  for (int k0=kbeg; k0<kend; k0+=32){
    f4v st0 = (f4v){0.f,0.f,0.f,0.f};
    f4v st1 = (f4v){0.f,0.f,0.f,0.f};
    const bf16* kp = Kbase + (size_t)k0*U_;
    #pragma unroll
    for (int uc=0;uc<4;uc++){
      bf8v kf0 = *reinterpret_cast<const bf8v*>(kp + uc*32);
      bf8v kf1 = *reinterpret_cast<const bf8v*>(kp + 16*U_ + uc*32);
      st0 = MFMA16(kf0, qf[uc], st0);
      st1 = MFMA16(kf1, qf[uc], st1);
    }
    float tm = fmaxf(fmaxf(fmaxf(st0[0],st0[1]),fmaxf(st0[2],st0[3])),
                     fmaxf(fmaxf(st1[0],st1[1]),fmaxf(st1[2],st1[3])));
    tm = fmaxf(tm, __shfl_xor(tm, 16));
    tm = fmaxf(tm, __shfl_xor(tm, 32));
    float mn    = fmaxf(mrow, tm);
    float alpha = __expf(mrow - mn);
    float p0[4], p1[4];
    float ts = 0.f;
    #pragma unroll
    for (int r=0;r<4;r++){
      p0[r] = __expf(st0[r]-mn);
      p1[r] = __expf(st1[r]-mn);
      ts += p0[r] + p1[r];
    }
    ts += __shfl_xor(ts, 16);
    ts += __shfl_xor(ts, 32);
    lrow = lrow*alpha + ts;
    mrow = mn;

    unsigned int w01 = (unsigned)f2bits(p0[0]) | ((unsigned)f2bits(p0[1])<<16);
    unsigned int w23 = (unsigned)f2bits(p0[2]) | ((unsigned)f2bits(p0[3])<<16);
    unsigned int x01 = (unsigned)f2bits(p1[0]) | ((unsigned)f2bits(p1[1])<<16);
    unsigned int x23 = (unsigned)f2bits(p1[2]) | ((unsigned)f2bits(p1[3])<<16);
    *reinterpret_cast<unsigned int*>(prow + 4*g)      = w01;
    *reinterpret_cast<unsigned int*>(prow + 4*g + 2)  = w23;
    *reinterpret_cast<unsigned int*>(prow + 16 + 4*g)     = x01;
    *reinterpret_cast<unsigned int*>(prow + 16 + 4*g + 2) = x23;

    float a0 = __shfl(alpha, g*4+0);
    float a1 = __shfl(alpha, g*4+1);
    float a2 = __shfl(alpha, g*4+2);
    float a3 = __shfl(alpha, g*4+3);
    #pragma unroll
    for (int uc=0;uc<8;uc++){
      o[uc][0]*=a0; o[uc][1]*=a1; o[uc][2]*=a2; o[uc][3]*=a3;
    }

    bf8v pa = *reinterpret_cast<const bf8v*>(&Plds[w][lq][g*8]);
    const bf16* vp = Vbase + k0;
    #pragma unroll
    for (int uc=0;uc<8;uc++){
      bf8v vf = *reinterpret_cast<const bf8v*>(vp + (size_t)uc*16*S_);
      o[uc] = MFMA16(pa, vf, o[uc]);
    }
  }

  // ---- cross-wave combine ----
  if (g==0){ mlds[w][lq] = mrow; llds[w][lq] = lrow; }
  __syncthreads();

  float fac[4];
  #pragma unroll
  for (int r=0;r<4;r++){
    int q = g*4+r;
    float M = fmaxf(fmaxf(mlds[0][q],mlds[1][q]),fmaxf(mlds[2][q],mlds[3][q]));
    fac[r] = __expf(mlds[w][q]-M);
  }
  #pragma unroll
  for (int uc=0;uc<8;uc++){
    #pragma unroll
    for (int r=0;r<4;r++){
      oacc[w][g*4+r][uc*16+lq] = o[uc][r]*fac[r];
    }
  }
  __syncthreads();

  const int tid  = threadIdx.x;
  const int c    = tid & 127;
  const int rb   = (tid >> 7) * 8;
  bf16* Op = O + (size_t)(b*S_ + q0)*U_;
  #pragma unroll
  for (int rr=0; rr<8; rr++){
    int q = rb + rr;
    float M = fmaxf(fmaxf(mlds[0][q],mlds[1][q]),fmaxf(mlds[2][q],mlds[3][q]));
    float L = llds[0][q]*__expf(mlds[0][q]-M) + llds[1][q]*__expf(mlds[1][q]-M)
            + llds[2][q]*__expf(mlds[2][q]-M) + llds[3][q]*__expf(mlds[3][q]-M);
    float val = oacc[0][q][c]+oacc[1][q][c]+oacc[2][q][c]+oacc[3][q][c];
    Op[(size_t)q*U_ + c] = __float2bfloat16(val / L);
  }
}

// ---------------- output projection + residual ----------------
// Y[BS,D] = O[BS,U] @ Wo[U,D] + b_o + X ; N split 2-way across blockIdx.y
__global__ __launch_bounds__(256) void oproj_kernel(const bf16* __restrict__ O,
                                                    const bf16* __restrict__ Wot,
                                                    const float* __restrict__ X,
                                                    const float* __restrict__ bo,
                                                    float* __restrict__ Y){
  const int w    = threadIdx.x >> 6;
  const int lane = threadIdx.x & 63;
  const int lq   = lane & 15;
  const int g    = lane >> 4;
  const int m0   = blockIdx.x*64 + w*16;
  const int n0   = blockIdx.y*128;

  f4v acc[8];
  #pragma unroll
  for (int i=0;i<8;i++) acc[i] = (f4v){0.f,0.f,0.f,0.f};

  const bf16* op = O + (size_t)(m0+lq)*U_ + g*8;
  #pragma unroll
  for (int k0=0;k0<U_;k0+=32){
    bf8v a = *reinterpret_cast<const bf8v*>(op + k0);
    #pragma unroll
    for (int nc=0;nc<8;nc++){
      bf8v bb = *reinterpret_cast<const bf8v*>(Wot + (size_t)(n0+nc*16+lq)*U_ + k0 + g*8);
      acc[nc] = MFMA16(a, bb, acc[nc]);
    }
  }

  #pragma unroll
  for (int nc=0;nc<8;nc++){
    int col = n0 + nc*16 + lq;
    float bias = bo[col];
    #pragma unroll
    for (int r=0;r<4;r++){
      int row = m0 + g*4 + r;
      Y[(size_t)row*D_ + col] = acc[nc][r] + bias + X[(size_t)row*D_ + col];
    }
  }
}

extern "C" void kernel_launch(void* const* d_in, const int* in_sizes, int n_in,
                              void* d_out, int out_size, void* d_ws, size_t ws_size,
                              hipStream_t stream) {
  (void)in_sizes; (void)n_in; (void)out_size; (void)ws_size;
  const float* X  = (const float*)d_in[0];
  const float* Wq = (const float*)d_in[1];
  const float* Wk = (const float*)d_in[2];
  const float* Wv = (const float*)d_in[3];
  const float* Wo = (const float*)d_in[4];
  const float* bo = (const float*)d_in[5];
  float* Y = (float*)d_out;

  char* ws = (char*)d_ws;
  bf16* Xb  = (bf16*)(ws + 0);          // BS*D*2    = 8388608
  bf16* Qb  = (bf16*)(ws + 8388608);    // BS*U*2    = 4194304
  bf16* Kb  = (bf16*)(ws + 12582912);   // BS*U*2
  bf16* Vt  = (bf16*)(ws + 16777216);   // BS*U*2 (transposed per batch)
  bf16* Ob  = (bf16*)(ws + 20971520);   // BS*U*2
  bf16* Wqt = (bf16*)(ws + 25165824);   // U*D*2 = 65536
  bf16* Wkt = (bf16*)(ws + 25231360);
  bf16* Wvt = (bf16*)(ws + 25296896);
  bf16* Wot = (bf16*)(ws + 25362432);

  convert_x_kernel<<<dim3(BS_*D_/4/256), dim3(256), 0, stream>>>(X, (unsigned short*)Xb);
  prep_w_kernel<<<dim3(512), dim3(256), 0, stream>>>(Wq, Wk, Wv, Wo, Wqt, Wkt, Wvt, Wot);
  qkv_kernel<<<dim3(BS_/64, 3), dim3(256), 0, stream>>>(Xb, Wqt, Wkt, Wvt, Qb, Kb, Vt);
  flash_kernel<<<dim3(S_/16, B_), dim3(256), 0, stream>>>(Qb, Kb, Vt, Ob);
  oproj_kernel<<<dim3(BS_/64, 2), dim3(256), 0, stream>>>(Ob, Wot, X, bo, Y);
}

// Round 3
// 115.874 us; speedup vs baseline: 1.7501x; 1.4779x over previous
//
#include <hip/hip_runtime.h>
#include <hip/hip_bf16.h>

#define B_ 8
#define S_ 2048
#define D_ 256
#define U_ 128
#define BS_ (B_*S_)

using bf16 = __hip_bfloat16;
typedef __attribute__((ext_vector_type(8))) __bf16 bf8v;      // MFMA A/B frag (4 VGPR)
typedef __attribute__((ext_vector_type(4))) float f4v;        // 16x16 C/D frag
typedef __attribute__((ext_vector_type(16))) float f16v;      // 32x32 C/D frag
typedef __attribute__((ext_vector_type(4))) float float4v;
typedef __attribute__((ext_vector_type(4))) unsigned short us4;
typedef __attribute__((ext_vector_type(8))) unsigned short us8;
typedef __attribute__((ext_vector_type(4))) unsigned int u4v;

#define MFMA16(a,b,c) __builtin_amdgcn_mfma_f32_16x16x32_bf16((a),(b),(c),0,0,0)
#define MFMA32(a,b,c) __builtin_amdgcn_mfma_f32_32x32x16_bf16((a),(b),(c),0,0,0)

__device__ __forceinline__ unsigned short f2bits(float f){
  return __builtin_bit_cast(unsigned short, __float2bfloat16(f));
}

// ---------------- prep: X fp32 -> bf16 ----------------
__global__ __launch_bounds__(256) void convert_x_kernel(const float* __restrict__ X,
                                                        unsigned short* __restrict__ Xb){
  int i = blockIdx.x*256 + threadIdx.x;             // BS_*D_/4 threads
  float4v v = reinterpret_cast<const float4v*>(X)[i];
  us4 r;
  r[0]=f2bits(v[0]); r[1]=f2bits(v[1]); r[2]=f2bits(v[2]); r[3]=f2bits(v[3]);
  reinterpret_cast<us4*>(Xb)[i] = r;
}

// ---------------- prep: weight transpose+convert ----------------
__global__ __launch_bounds__(256) void prep_w_kernel(const float* __restrict__ Wq,
                                                     const float* __restrict__ Wk,
                                                     const float* __restrict__ Wv,
                                                     const float* __restrict__ Wo,
                                                     bf16* __restrict__ Wqt,
                                                     bf16* __restrict__ Wkt,
                                                     bf16* __restrict__ Wvt,
                                                     bf16* __restrict__ Wot){
  int t = blockIdx.x*256 + threadIdx.x;             // 4*32768 threads
  int s = t >> 15;
  int idx = t & 32767;
  if (s < 3){
    const float* src = (s==0)?Wq:((s==1)?Wk:Wv);
    bf16* dst = (s==0)?Wqt:((s==1)?Wkt:Wvt);
    int u = idx >> 8;          // /D_ = 256
    int d = idx & 255;
    dst[(size_t)u*D_ + d] = __float2bfloat16(src[(size_t)d*U_ + u]);
  } else {
    int dd = idx >> 7;         // /U_ = 128
    int u  = idx & 127;
    Wot[(size_t)dd*U_ + u] = __float2bfloat16(Wo[(size_t)u*D_ + dd]);
  }
}

// ---------------- QKV projection GEMM ----------------
__global__ __launch_bounds__(256) void qkv_kernel(const bf16* __restrict__ Xb,
                                                  const bf16* __restrict__ Wqt,
                                                  const bf16* __restrict__ Wkt,
                                                  const bf16* __restrict__ Wvt,
                                                  bf16* __restrict__ Q,
                                                  bf16* __restrict__ K,
                                                  bf16* __restrict__ Vt){
  const int which = blockIdx.y;
  const bf16* Wt = (which==0) ? Wqt : ((which==1) ? Wkt : Wvt);
  const int w    = threadIdx.x >> 6;
  const int lane = threadIdx.x & 63;
  const int lq   = lane & 15;
  const int g    = lane >> 4;
  const int m0   = blockIdx.x*64 + w*16;

  f4v acc[8];
  #pragma unroll
  for (int i=0;i<8;i++) acc[i] = (f4v){0.f,0.f,0.f,0.f};

  const bf16* xp = Xb + (size_t)(m0+lq)*D_ + g*8;
  #pragma unroll
  for (int k0=0;k0<D_;k0+=32){
    bf8v a = *reinterpret_cast<const bf8v*>(xp + k0);
    #pragma unroll
    for (int nc=0;nc<8;nc++){
      bf8v b = *reinterpret_cast<const bf8v*>(Wt + (size_t)(nc*16+lq)*D_ + k0 + g*8);
      acc[nc] = MFMA16(a, b, acc[nc]);
    }
  }

  if (which==0){
    const float qscale = 0.08838834764831845f;      // 1/sqrt(U)
    #pragma unroll
    for (int nc=0;nc<8;nc++){
      #pragma unroll
      for (int r=0;r<4;r++){
        Q[(size_t)(m0+g*4+r)*U_ + nc*16+lq] = __float2bfloat16(acc[nc][r]*qscale);
      }
    }
  } else if (which==1){
    #pragma unroll
    for (int nc=0;nc<8;nc++){
      #pragma unroll
      for (int r=0;r<4;r++){
        K[(size_t)(m0+g*4+r)*U_ + nc*16+lq] = __float2bfloat16(acc[nc][r]);
      }
    }
  } else {
    #pragma unroll
    for (int nc=0;nc<8;nc++){
      #pragma unroll
      for (int r=0;r<4;r++){
        int m = m0 + g*4 + r;
        int b = m >> 11;               // /S_
        int s = m & (S_-1);
        Vt[((size_t)b*U_ + nc*16+lq)*S_ + s] = __float2bfloat16(acc[nc][r]);
      }
    }
  }
}

// ---------------- flash attention: 32x32 MFMA, in-register softmax ----------------
// grid = 512 blocks: batch = blockIdx.x & 7 (XCD-aligned), q-tile = blockIdx.x >> 3.
// 4 waves/block; wave w owns KV rows [w*512, (w+1)*512). 32 q-rows per block.
// QK^T swapped: S^T = mfma32(K_frag, Q_frag): C col = q = lane&31, rows = k.
// PV swapped:   O^T = mfma32(Vt_frag, P_frag): C col = q = lane&31, rows = u.
// => softmax stats and rescale are per-lane scalars. P re-layout in-register.
__global__ __launch_bounds__(256) void flash_kernel(const bf16* __restrict__ Q,
                                                    const bf16* __restrict__ K,
                                                    const bf16* __restrict__ Vt,
                                                    bf16* __restrict__ O){
  __shared__ float Olds[4][128][33];   // per-wave O^T partial [u][q], pad 33 vs conflicts
  __shared__ float mlds[4][32];
  __shared__ float llds[4][32];

  const int n    = blockIdx.x;
  const int b    = n & 7;
  const int qt   = n >> 3;
  const int w    = threadIdx.x >> 6;
  const int lane = threadIdx.x & 63;
  const int l5   = lane & 31;
  const int hi   = lane >> 5;
  const int q0   = qt * 32;

  // Q B-frags (pre-scaled by 1/sqrt(U)): lane holds Q[q0+l5][uc*16 + hi*8 + j]
  const bf16* Qp = Q + (size_t)(b*S_ + q0 + l5)*U_ + hi*8;
  bf8v qf[8];
  #pragma unroll
  for (int uc=0; uc<8; uc++) qf[uc] = *reinterpret_cast<const bf8v*>(Qp + uc*16);

  f16v o[4];
  #pragma unroll
  for (int uc=0; uc<4; uc++)
    #pragma unroll
    for (int r=0; r<16; r++) o[uc][r] = 0.f;

  float mrow = -1e30f, lrow = 0.f;

  const bf16* Kb = K  + (size_t)(b*S_ + l5)*U_ + hi*8;
  const bf16* Vb = Vt + ((size_t)b*U_ + l5)*S_ + hi*8;

  const int kbeg = w*(S_/4), kend = kbeg + S_/4;
  for (int k0=kbeg; k0<kend; k0+=32){
    // ---- QK^T ----
    f16v st0, st1;
    #pragma unroll
    for (int r=0;r<16;r++){ st0[r]=0.f; st1[r]=0.f; }
    const bf16* kp = Kb + (size_t)k0*U_;
    #pragma unroll
    for (int uc=0; uc<4; uc++){
      bf8v ka = *reinterpret_cast<const bf8v*>(kp + uc*32);
      bf8v kc = *reinterpret_cast<const bf8v*>(kp + uc*32 + 16);
      st0 = MFMA32(ka, qf[2*uc],   st0);
      st1 = MFMA32(kc, qf[2*uc+1], st1);
    }
    float p[16];
    #pragma unroll
    for (int r=0;r<16;r++) p[r] = st0[r] + st1[r];

    // ---- softmax stats (lane-local: col q = l5, rows k) ----
    float tm = p[0];
    #pragma unroll
    for (int r=1;r<16;r++) tm = fmaxf(tm, p[r]);
    tm = fmaxf(tm, __shfl_xor(tm, 32));

    if (!__all(tm <= mrow + 8.0f)){          // T13 defer-max
      float mn    = fmaxf(mrow, tm);
      float alpha = __expf(mrow - mn);
      lrow *= alpha;
      #pragma unroll
      for (int uc=0;uc<4;uc++)
        #pragma unroll
        for (int r=0;r<16;r++) o[uc][r] *= alpha;
      mrow = mn;
    }

    float ts = 0.f;
    #pragma unroll
    for (int r=0;r<16;r++){ p[r] = __expf(p[r]-mrow); ts += p[r]; }
    ts += __shfl_xor(ts, 32);
    lrow += ts;

    // ---- P -> bf16 A/B-frags in-register ----
    // lane's p[r] = P[q=l5][k=(r&3)+8*(r>>2)+4*hi]
    unsigned c0 = (unsigned)f2bits(p[0])  | ((unsigned)f2bits(p[1])<<16);
    unsigned c1 = (unsigned)f2bits(p[2])  | ((unsigned)f2bits(p[3])<<16);
    unsigned c2 = (unsigned)f2bits(p[4])  | ((unsigned)f2bits(p[5])<<16);
    unsigned c3 = (unsigned)f2bits(p[6])  | ((unsigned)f2bits(p[7])<<16);
    unsigned c4 = (unsigned)f2bits(p[8])  | ((unsigned)f2bits(p[9])<<16);
    unsigned c5 = (unsigned)f2bits(p[10]) | ((unsigned)f2bits(p[11])<<16);
    unsigned c6 = (unsigned)f2bits(p[12]) | ((unsigned)f2bits(p[13])<<16);
    unsigned c7 = (unsigned)f2bits(p[14]) | ((unsigned)f2bits(p[15])<<16);
    unsigned s0 = (unsigned)__shfl_xor((int)c0,32);
    unsigned s1 = (unsigned)__shfl_xor((int)c1,32);
    unsigned s2 = (unsigned)__shfl_xor((int)c2,32);
    unsigned s3 = (unsigned)__shfl_xor((int)c3,32);
    unsigned s4 = (unsigned)__shfl_xor((int)c4,32);
    unsigned s5 = (unsigned)__shfl_xor((int)c5,32);
    unsigned s6 = (unsigned)__shfl_xor((int)c6,32);
    unsigned s7 = (unsigned)__shfl_xor((int)c7,32);
    u4v w0v, w1v;
    w0v[0] = hi ? s2 : c0;  w0v[1] = hi ? s3 : c1;
    w0v[2] = hi ? c2 : s0;  w0v[3] = hi ? c3 : s1;
    w1v[0] = hi ? s6 : c4;  w1v[1] = hi ? s7 : c5;
    w1v[2] = hi ? c6 : s4;  w1v[3] = hi ? c7 : s5;
    bf8v pa0 = __builtin_bit_cast(bf8v, w0v);   // P[q=l5][k = hi*8+j]      (k 0..15)
    bf8v pa1 = __builtin_bit_cast(bf8v, w1v);   // P[q=l5][k = 16+hi*8+j]   (k 16..31)

    // ---- PV: O^T += V^T-frag x P-frag ----
    const bf16* vp = Vb + k0;
    #pragma unroll
    for (int uc=0; uc<4; uc++){
      bf8v v0 = *reinterpret_cast<const bf8v*>(vp + (size_t)(uc*32)*S_);
      bf8v v1 = *reinterpret_cast<const bf8v*>(vp + (size_t)(uc*32)*S_ + 16);
      o[uc] = MFMA32(v0, pa0, o[uc]);
      o[uc] = MFMA32(v1, pa1, o[uc]);
    }
  }

  // ---- write per-wave partials ----
  if (hi==0){ mlds[w][l5] = mrow; llds[w][l5] = lrow; }
  #pragma unroll
  for (int uc=0; uc<4; uc++){
    #pragma unroll
    for (int r=0; r<16; r++){
      int u = uc*32 + (r&3) + 8*(r>>2) + 4*hi;
      Olds[w][u][l5] = o[uc][r];
    }
  }
  __syncthreads();

  // ---- cross-wave combine: thread -> (q = tid>>3, u block = tid&7) ----
  const int qrow = threadIdx.x >> 3;
  const int ub   = threadIdx.x & 7;
  float m0v = mlds[0][qrow], m1v = mlds[1][qrow], m2v = mlds[2][qrow], m3v = mlds[3][qrow];
  float M  = fmaxf(fmaxf(m0v,m1v), fmaxf(m2v,m3v));
  float e0 = __expf(m0v-M), e1 = __expf(m1v-M), e2 = __expf(m2v-M), e3 = __expf(m3v-M);
  float L  = llds[0][qrow]*e0 + llds[1][qrow]*e1 + llds[2][qrow]*e2 + llds[3][qrow]*e3;
  float inv = 1.0f / L;
  us8 out0, out1;
  #pragma unroll
  for (int j=0;j<16;j++){
    int u = ub*16 + j;
    float val = e0*Olds[0][u][qrow] + e1*Olds[1][u][qrow]
              + e2*Olds[2][u][qrow] + e3*Olds[3][u][qrow];
    unsigned short bb = f2bits(val*inv);
    if (j<8) out0[j] = bb; else out1[j-8] = bb;
  }
  bf16* Op = O + (size_t)(b*S_ + q0 + qrow)*U_ + ub*16;
  *reinterpret_cast<us8*>(Op)     = out0;
  *reinterpret_cast<us8*>(Op + 8) = out1;
}

// ---------------- output projection + residual ----------------
__global__ __launch_bounds__(256) void oproj_kernel(const bf16* __restrict__ O,
                                                    const bf16* __restrict__ Wot,
                                                    const float* __restrict__ X,
                                                    const float* __restrict__ bo,
                                                    float* __restrict__ Y){
  const int w    = threadIdx.x >> 6;
  const int lane = threadIdx.x & 63;
  const int lq   = lane & 15;
  const int g    = lane >> 4;
  const int m0   = blockIdx.x*64 + w*16;
  const int n0   = blockIdx.y*128;

  f4v acc[8];
  #pragma unroll
  for (int i=0;i<8;i++) acc[i] = (f4v){0.f,0.f,0.f,0.f};

  const bf16* op = O + (size_t)(m0+lq)*U_ + g*8;
  #pragma unroll
  for (int k0=0;k0<U_;k0+=32){
    bf8v a = *reinterpret_cast<const bf8v*>(op + k0);
    #pragma unroll
    for (int nc=0;nc<8;nc++){
      bf8v bb = *reinterpret_cast<const bf8v*>(Wot + (size_t)(n0+nc*16+lq)*U_ + k0 + g*8);
      acc[nc] = MFMA16(a, bb, acc[nc]);
    }
  }

  #pragma unroll
  for (int nc=0;nc<8;nc++){
    int col = n0 + nc*16 + lq;
    float bias = bo[col];
    #pragma unroll
    for (int r=0;r<4;r++){
      int row = m0 + g*4 + r;
      Y[(size_t)row*D_ + col] = acc[nc][r] + bias + X[(size_t)row*D_ + col];
    }
  }
}

extern "C" void kernel_launch(void* const* d_in, const int* in_sizes, int n_in,
                              void* d_out, int out_size, void* d_ws, size_t ws_size,
                              hipStream_t stream) {
  (void)in_sizes; (void)n_in; (void)out_size; (void)ws_size;
  const float* X  = (const float*)d_in[0];
  const float* Wq = (const float*)d_in[1];
  const float* Wk = (const float*)d_in[2];
  const float* Wv = (const float*)d_in[3];
  const float* Wo = (const float*)d_in[4];
  const float* bo = (const float*)d_in[5];
  float* Y = (float*)d_out;

  char* ws = (char*)d_ws;
  bf16* Xb  = (bf16*)(ws + 0);          // BS*D*2    = 8388608
  bf16* Qb  = (bf16*)(ws + 8388608);    // BS*U*2    = 4194304
  bf16* Kb  = (bf16*)(ws + 12582912);   // BS*U*2
  bf16* Vt  = (bf16*)(ws + 16777216);   // BS*U*2 (transposed per batch)
  bf16* Ob  = (bf16*)(ws + 20971520);   // BS*U*2
  bf16* Wqt = (bf16*)(ws + 25165824);   // U*D*2 = 65536
  bf16* Wkt = (bf16*)(ws + 25231360);
  bf16* Wvt = (bf16*)(ws + 25296896);
  bf16* Wot = (bf16*)(ws + 25362432);

  convert_x_kernel<<<dim3(BS_*D_/4/256), dim3(256), 0, stream>>>(X, (unsigned short*)Xb);
  prep_w_kernel<<<dim3(512), dim3(256), 0, stream>>>(Wq, Wk, Wv, Wo, Wqt, Wkt, Wvt, Wot);
  qkv_kernel<<<dim3(BS_/64, 3), dim3(256), 0, stream>>>(Xb, Wqt, Wkt, Wvt, Qb, Kb, Vt);
  flash_kernel<<<dim3(512), dim3(256), 0, stream>>>(Qb, Kb, Vt, Ob);
  oproj_kernel<<<dim3(BS_/64, 2), dim3(256), 0, stream>>>(Ob, Wot, X, bo, Y);
}